// Round 2
// baseline (140.162 us; speedup 1.0000x reference)
//
#include <hip/hip_runtime.h>

// Problem constants (fixed by setup_inputs in the reference).
#define BB 128
#define CC 3
#define HH 224
#define WW 224
#define PP 16

#define W4 (WW / 4)               // 56 float4 per row
#define CHAN4 (HH * W4)           // 12544 float4 per channel = 49 * 256 (exact)
#define PER_IMG4 (CC * CHAN4)     // 37632 float4 per image
#define PBLK (CHAN4 / 256)        // 49 position-blocks per channel

// Global mask layout: one bit per pixel, row-major, 8 words per row
// (224 bits -> 7 words used, padded to 8 for cheap indexing).
#define MROW 8
#define MIMG (HH * MROW)                      // 1792 words per image
#define MASK_BYTES ((size_t)BB * MIMG * 4)    // 917504 B

typedef float vfloat4 __attribute__((ext_vector_type(4)));

// ---------------------------------------------------------------------------
// Kernel A: one block per image builds the full 224-row occlusion bitmask in
// LDS and dumps it to global workspace (7 KB/image). Regular (cacheable)
// stores so the apply kernel's mask reads hit L2/L3.
// ---------------------------------------------------------------------------
__global__ __launch_bounds__(256) void build_masks(
        unsigned int* __restrict__ masks, const int* __restrict__ px,
        const int* __restrict__ py, int N) {
    const int b = blockIdx.x;
    const int t = threadIdx.x;

    __shared__ unsigned int rb[MIMG];   // 7168 B
    __shared__ int sx[128], sy[128];

    for (int i = t; i < MIMG; i += 256) rb[i] = 0u;
    if (t < N) { sx[t] = px[b * N + t]; sy[t] = py[b * N + t]; }
    __syncthreads();

    // One (point, patch-row) pair per iteration: N*PP = 1568 pairs.
    for (int idx = t; idx < N * PP; idx += 256) {
        const int pt = idx >> 4;        // PP == 16
        const int r  = idx & (PP - 1);
        const int x  = sx[pt] + r;      // image row, <= 208+15 = 223
        const int y  = sy[pt];          // first column of the 16-wide span
        unsigned long long mm = 0xFFFFull << (y & 31);
        const int w = y >> 5;
        atomicOr(&rb[x * MROW + w], (unsigned int)mm);
        const unsigned int hi = (unsigned int)(mm >> 32);
        if (hi) atomicOr(&rb[x * MROW + w + 1], hi);
    }
    __syncthreads();

    for (int i = t; i < MIMG; i += 256) masks[b * MIMG + i] = rb[i];
}

// ---------------------------------------------------------------------------
// Kernel B: pure streaming, TWO images per block (same 256 positions in
// images 2q and 2q+1). Doubles per-thread MLP: 2 independent mask loads
// issue back-to-back, then two independent 3-load/3-store chains overlap --
// the second chain's HBM latency hides under the first's. Coalescing per
// instruction unchanged (64 lanes x 16 B contiguous). Fully-masked float4s
// still skip the global load (exec-masked lanes drop dead cache lines).
// ---------------------------------------------------------------------------
__global__ __launch_bounds__(256) void occl_apply2(
        vfloat4* __restrict__ out, const vfloat4* __restrict__ imgs,
        const unsigned int* __restrict__ masks) {
    const int t   = threadIdx.x;
    const int bq  = blockIdx.x / PBLK;          // image pair index (0..63)
    const int pb  = blockIdx.x % PBLK;          // position block (0..48)
    const int b0  = bq * 2;

    const int p  = pb * 256 + t;                // pos within channel
    const int w4 = p % W4;
    const int h  = p / W4;
    const int mi = h * MROW + (w4 >> 3);
    const int sh = (w4 & 7) * 4;

    // Both mask loads issue before either chain waits.
    const unsigned int wordA = masks[b0 * MIMG + mi];
    const unsigned int wordB = masks[b0 * MIMG + MIMG + mi];
    const unsigned int mA = (wordA >> sh) & 0xFu;
    const unsigned int mB = (wordB >> sh) & 0xFu;

    const size_t fA = (size_t)b0 * PER_IMG4 + p;     // image A, channel 0
    const size_t fB = fA + PER_IMG4;                 // image B, channel 0

    vfloat4 z = {0.f, 0.f, 0.f, 0.f};
    vfloat4 a0 = z, a1 = z, a2 = z;
    vfloat4 c0 = z, c1 = z, c2 = z;
    if (mA != 0xFu) {
        a0 = __builtin_nontemporal_load(&imgs[fA]);
        a1 = __builtin_nontemporal_load(&imgs[fA + CHAN4]);
        a2 = __builtin_nontemporal_load(&imgs[fA + 2 * CHAN4]);
    }
    if (mB != 0xFu) {
        c0 = __builtin_nontemporal_load(&imgs[fB]);
        c1 = __builtin_nontemporal_load(&imgs[fB + CHAN4]);
        c2 = __builtin_nontemporal_load(&imgs[fB + 2 * CHAN4]);
    }
    if (mA & 1u) { a0.x = 0.f; a1.x = 0.f; a2.x = 0.f; }
    if (mA & 2u) { a0.y = 0.f; a1.y = 0.f; a2.y = 0.f; }
    if (mA & 4u) { a0.z = 0.f; a1.z = 0.f; a2.z = 0.f; }
    if (mA & 8u) { a0.w = 0.f; a1.w = 0.f; a2.w = 0.f; }
    if (mB & 1u) { c0.x = 0.f; c1.x = 0.f; c2.x = 0.f; }
    if (mB & 2u) { c0.y = 0.f; c1.y = 0.f; c2.y = 0.f; }
    if (mB & 4u) { c0.z = 0.f; c1.z = 0.f; c2.z = 0.f; }
    if (mB & 8u) { c0.w = 0.f; c1.w = 0.f; c2.w = 0.f; }

    __builtin_nontemporal_store(a0, &out[fA]);
    __builtin_nontemporal_store(a1, &out[fA + CHAN4]);
    __builtin_nontemporal_store(a2, &out[fA + 2 * CHAN4]);
    __builtin_nontemporal_store(c0, &out[fB]);
    __builtin_nontemporal_store(c1, &out[fB + CHAN4]);
    __builtin_nontemporal_store(c2, &out[fB + 2 * CHAN4]);
}

// ---------------------------------------------------------------------------
// Fallback: channel-fused single kernel with per-block 6-row mask build.
// Used only if the workspace is too small for the global mask.
// ---------------------------------------------------------------------------
#define NROWS 6
__global__ __launch_bounds__(256) void occl_fused(
        vfloat4* __restrict__ out, const vfloat4* __restrict__ imgs,
        const int* __restrict__ px, const int* __restrict__ py, int N) {
    const int t     = threadIdx.x;
    const int b     = blockIdx.x / PBLK;
    const int posF0 = (blockIdx.x % PBLK) * 256;
    const int h0    = posF0 / W4;

    __shared__ unsigned int rowbits[NROWS * 7];
    if (t < NROWS * 7) rowbits[t] = 0u;
    __syncthreads();

    if (t < N) {
        int x = px[b * N + t];
        int y = py[b * N + t];
        int lo = x > h0 ? x : h0;
        int hi = (x + PP < h0 + NROWS) ? (x + PP) : (h0 + NROWS);
        if (lo < hi) {
            unsigned long long mm = 0xFFFFull << (y & 31);
            unsigned int lo32 = (unsigned int)mm;
            unsigned int hi32 = (unsigned int)(mm >> 32);
            int woff = y >> 5;
            for (int h = lo; h < hi; ++h) {
                int base = (h - h0) * 7 + woff;
                atomicOr(&rowbits[base], lo32);
                if (hi32) atomicOr(&rowbits[base + 1], hi32);
            }
        }
    }
    __syncthreads();

    int p  = posF0 + t;
    int w4 = p % W4;
    int h  = p / W4;
    unsigned int word = rowbits[(h - h0) * 7 + (w4 >> 3)];
    unsigned int m4 = (word >> ((w4 & 7) * 4)) & 0xFu;

    size_t f0 = (size_t)b * PER_IMG4 + p;
    vfloat4 z = {0.f, 0.f, 0.f, 0.f};
    vfloat4 v0 = z, v1 = z, v2 = z;
    if (m4 != 0xFu) {
        v0 = __builtin_nontemporal_load(&imgs[f0]);
        v1 = __builtin_nontemporal_load(&imgs[f0 + CHAN4]);
        v2 = __builtin_nontemporal_load(&imgs[f0 + 2 * CHAN4]);
        if (m4 & 1u) { v0.x = 0.f; v1.x = 0.f; v2.x = 0.f; }
        if (m4 & 2u) { v0.y = 0.f; v1.y = 0.f; v2.y = 0.f; }
        if (m4 & 4u) { v0.z = 0.f; v1.z = 0.f; v2.z = 0.f; }
        if (m4 & 8u) { v0.w = 0.f; v1.w = 0.f; v2.w = 0.f; }
    }
    __builtin_nontemporal_store(v0, &out[f0]);
    __builtin_nontemporal_store(v1, &out[f0 + CHAN4]);
    __builtin_nontemporal_store(v2, &out[f0 + 2 * CHAN4]);
}

extern "C" void kernel_launch(void* const* d_in, const int* in_sizes, int n_in,
                              void* d_out, int out_size, void* d_ws, size_t ws_size,
                              hipStream_t stream) {
    const float* imgs = (const float*)d_in[0];
    const int*   px   = (const int*)d_in[1];
    const int*   py   = (const int*)d_in[2];
    float*       out  = (float*)d_out;

    const int N = in_sizes[1] / BB;  // points per image (98)

    if (ws_size >= MASK_BYTES && d_ws != nullptr) {
        unsigned int* masks = (unsigned int*)d_ws;
        build_masks<<<BB, 256, 0, stream>>>(masks, px, py, N);
        occl_apply2<<<(BB / 2) * PBLK, 256, 0, stream>>>(
            (vfloat4*)out, (const vfloat4*)imgs, masks);
    } else {
        occl_fused<<<BB * PBLK, 256, 0, stream>>>(
            (vfloat4*)out, (const vfloat4*)imgs, px, py, N);
    }
}

// Round 3
// 134.749 us; speedup vs baseline: 1.0402x; 1.0402x over previous
//
#include <hip/hip_runtime.h>

// Problem constants (fixed by setup_inputs in the reference).
#define BB 128
#define CC 3
#define HH 224
#define WW 224
#define PP 16

#define W4 (WW / 4)               // 56 float4 per row
#define CHAN4 (HH * W4)           // 12544 float4 per channel = 49 * 256 (exact)
#define PER_IMG4 (CC * CHAN4)     // 37632 float4 per image
#define NROWS 6                   // 256 (h,w4) positions span at most 6 rows
#define NBLK (BB * (CHAN4 / 256)) // 128 * 49 = 6272 blocks

typedef float vfloat4 __attribute__((ext_vector_type(4)));

// ---------------------------------------------------------------------------
// Best-measured structure (R0, 136.0 us): channel-fused, each block owns 256
// (h,w4) positions of ONE image (mask is channel-invariant), builds a 6-row
// LDS bitmask from the point list, then streams all 3 channels at those
// positions. R1 (global-mask split) and R2 (2-image fusion) both regressed:
// the kernel portion is latency-hidden and BW-bound; extra dispatches and
// smaller grids only add cost.
//
// One free change vs R0: px/py global loads are issued BEFORE the LDS zero +
// first barrier, so their latency hides under the zeroing instead of
// serializing the mask-build critical path.
// ---------------------------------------------------------------------------
__global__ __launch_bounds__(256) void occl_fused(
        vfloat4* __restrict__ out, const vfloat4* __restrict__ imgs,
        const int* __restrict__ px, const int* __restrict__ py, int N) {
    const int t     = threadIdx.x;
    const int b     = blockIdx.x / (CHAN4 / 256);    // image index
    const int posF0 = (blockIdx.x % (CHAN4 / 256)) * 256;
    const int h0    = posF0 / W4;                    // first row in window

    __shared__ unsigned int rowbits[NROWS * 7];      // 6 rows x 7 mask words

    // Issue point loads first -- latency overlaps the LDS zero + barrier.
    int x = 0, y = 0;
    if (t < N) {
        x = px[b * N + t];
        y = py[b * N + t];
    }
    if (t < NROWS * 7) rowbits[t] = 0u;
    __syncthreads();

    // Build: one patch per thread (N=98 < 256), clipped to [h0, h0+6).
    if (t < N) {
        int lo = x > h0 ? x : h0;
        int hi = (x + PP < h0 + NROWS) ? (x + PP) : (h0 + NROWS);
        if (lo < hi) {
            unsigned long long mm = 0xFFFFull << (y & 31);
            unsigned int lo32 = (unsigned int)mm;
            unsigned int hi32 = (unsigned int)(mm >> 32);
            int woff = y >> 5;
            for (int h = lo; h < hi; ++h) {
                int base = (h - h0) * 7 + woff;
                atomicOr(&rowbits[base], lo32);
                if (hi32) atomicOr(&rowbits[base + 1], hi32);
            }
        }
    }
    __syncthreads();

    // Apply to all 3 channels at this (h,w4) position.
    int p  = posF0 + t;                 // position within channel [0, CHAN4)
    int w4 = p % W4;
    int h  = p / W4;
    unsigned int word = rowbits[(h - h0) * 7 + (w4 >> 3)];
    unsigned int m4 = (word >> ((w4 & 7) * 4)) & 0xFu;

    size_t f0 = (size_t)b * PER_IMG4 + p;            // channel 0
    vfloat4 z = {0.f, 0.f, 0.f, 0.f};
    vfloat4 v0 = z, v1 = z, v2 = z;
    if (m4 != 0xFu) {                    // skip loads where all 4 px masked
        v0 = __builtin_nontemporal_load(&imgs[f0]);
        v1 = __builtin_nontemporal_load(&imgs[f0 + CHAN4]);
        v2 = __builtin_nontemporal_load(&imgs[f0 + 2 * CHAN4]);
        if (m4 & 1u) { v0.x = 0.f; v1.x = 0.f; v2.x = 0.f; }
        if (m4 & 2u) { v0.y = 0.f; v1.y = 0.f; v2.y = 0.f; }
        if (m4 & 4u) { v0.z = 0.f; v1.z = 0.f; v2.z = 0.f; }
        if (m4 & 8u) { v0.w = 0.f; v1.w = 0.f; v2.w = 0.f; }
    }
    __builtin_nontemporal_store(v0, &out[f0]);
    __builtin_nontemporal_store(v1, &out[f0 + CHAN4]);
    __builtin_nontemporal_store(v2, &out[f0 + 2 * CHAN4]);
}

extern "C" void kernel_launch(void* const* d_in, const int* in_sizes, int n_in,
                              void* d_out, int out_size, void* d_ws, size_t ws_size,
                              hipStream_t stream) {
    const float* imgs = (const float*)d_in[0];
    const int*   px   = (const int*)d_in[1];
    const int*   py   = (const int*)d_in[2];
    float*       out  = (float*)d_out;

    const int N = in_sizes[1] / BB;  // points per image (98)

    occl_fused<<<NBLK, 256, 0, stream>>>(
        (vfloat4*)out, (const vfloat4*)imgs, px, py, N);
}